// Round 1
// baseline (3638.904 us; speedup 1.0000x reference)
//
#include <hip/hip_runtime.h>

#define N_NODES 50000
#define HIDDEN  256
#define ANNOT   32
#define NTYPES  4
#define EPT     75000

typedef __attribute__((ext_vector_type(4))) float    f32x4;
typedef __attribute__((ext_vector_type(8))) _Float16 f16x8;
typedef _Float16 half_t;

#define MFMA16(a,b,c) __builtin_amdgcn_mfma_f32_16x16x32_f16((a),(b),(c),0,0,0)

// ---------------- weight fp32 -> fp16 convert ----------------
__global__ void k_cvt(const float* __restrict__ in, half_t* __restrict__ out, int n) {
    int i = blockIdx.x * blockDim.x + threadIdx.x;
    if (i < n) out[i] = (half_t)in[i];
}

// ---------------- h0 = [x | annot] @ W_hid^T + b_hid ----------------
// block: 256 thr (4 waves), tile 64 rows x 256 cols, K = 288 (9 steps of 32)
__global__ __launch_bounds__(256) void k_init(
    const float* __restrict__ x, const float* __restrict__ annot,
    const half_t* __restrict__ Whid16, const float* __restrict__ b_hid,
    float* __restrict__ h, half_t* __restrict__ h16)
{
    __shared__ half_t Atile[4 * 64 * 8];   // [kchunk][row][8]
    const int tid  = threadIdx.x;
    const int lane = tid & 63;
    const int wave = tid >> 6;
    const int n0   = blockIdx.x * 64;

    f32x4 acc[4][4] = {};   // [rt][nt]

    for (int ks = 0; ks < 9; ++ks) {
        const int k0 = ks * 32;
        { // stage: thread t -> chunk c = t>>6, row r = t&63
            const int c = tid >> 6, r = tid & 63;
            const int node = n0 + r;
            f16x8 hv = {};
            if (node < N_NODES) {
                const int kk = k0 + c * 8;
                const float* s = (kk < HIDDEN) ? (x + (size_t)node * HIDDEN + kk)
                                               : (annot + (size_t)node * ANNOT + (kk - HIDDEN));
                const float4* s4 = reinterpret_cast<const float4*>(s);
                float4 a0 = s4[0], a1 = s4[1];
                hv[0]=(half_t)a0.x; hv[1]=(half_t)a0.y; hv[2]=(half_t)a0.z; hv[3]=(half_t)a0.w;
                hv[4]=(half_t)a1.x; hv[5]=(half_t)a1.y; hv[6]=(half_t)a1.z; hv[7]=(half_t)a1.w;
            }
            *reinterpret_cast<f16x8*>(&Atile[(c * 64 + r) * 8]) = hv;
        }
        __syncthreads();
        const int kc = lane >> 4, rl = lane & 15;
        f16x8 af[4];
        #pragma unroll
        for (int rt = 0; rt < 4; ++rt)
            af[rt] = *reinterpret_cast<const f16x8*>(&Atile[(kc * 64 + rt * 16 + rl) * 8]);
        #pragma unroll
        for (int nt = 0; nt < 4; ++nt) {
            const int col = wave * 64 + nt * 16 + rl;
            f16x8 bf = *reinterpret_cast<const f16x8*>(&Whid16[col * 288 + k0 + kc * 8]);
            #pragma unroll
            for (int rt = 0; rt < 4; ++rt)
                acc[rt][nt] = MFMA16(af[rt], bf, acc[rt][nt]);
        }
        __syncthreads();
    }

    const int rl = lane & 15, rg = lane >> 4;
    #pragma unroll
    for (int rt = 0; rt < 4; ++rt)
        #pragma unroll
        for (int i = 0; i < 4; ++i) {
            const int row = n0 + rt * 16 + rg * 4 + i;
            if (row >= N_NODES) continue;
            #pragma unroll
            for (int nt = 0; nt < 4; ++nt) {
                const int col = wave * 64 + nt * 16 + rl;
                float v = acc[rt][nt][i] + b_hid[col];
                h[(size_t)row * HIDDEN + col]   = v;
                h16[(size_t)row * HIDDEN + col] = (half_t)v;
            }
        }
}

// ---------------- per-type message GEMM + scatter-add ----------------
// grid (ceil(EPT/64), 4); tile 64 edges x 256 cols, K = 256
__global__ __launch_bounds__(256) void k_msgs(
    const half_t* __restrict__ h16,
    const int* __restrict__ edges,          // (4, EPT, 2) int32
    const half_t* __restrict__ Wmsg16,      // (2,4,256,256)
    const float* __restrict__ b_msg,        // (2,4,256)
    float* __restrict__ incoming,
    int layer)
{
    __shared__ half_t Atile[4 * 64 * 8];
    __shared__ int s_src[64];
    __shared__ int s_tgt[64];
    const int tid  = threadIdx.x;
    const int lane = tid & 63;
    const int wave = tid >> 6;
    const int t    = blockIdx.y;
    const int e0   = blockIdx.x * 64;

    if (tid < 64) {
        const int e = e0 + tid;
        int2 st = make_int2(0, 0);
        if (e < EPT) st = *reinterpret_cast<const int2*>(&edges[((size_t)t * EPT + e) * 2]);
        s_src[tid] = st.x;
        s_tgt[tid] = st.y;
    }
    __syncthreads();

    const half_t* W  = Wmsg16 + ((size_t)(layer * NTYPES + t)) * HIDDEN * HIDDEN;
    const float*  bm = b_msg + (size_t)(layer * NTYPES + t) * HIDDEN;

    f32x4 acc[4][4] = {};

    for (int ks = 0; ks < 8; ++ks) {
        const int k0 = ks * 32;
        {
            const int c = tid >> 6, r = tid & 63;
            f16x8 hv = {};
            if (e0 + r < EPT) {
                const int src = s_src[r];
                hv = *reinterpret_cast<const f16x8*>(&h16[(size_t)src * HIDDEN + k0 + c * 8]);
            }
            *reinterpret_cast<f16x8*>(&Atile[(c * 64 + r) * 8]) = hv;
        }
        __syncthreads();
        const int kc = lane >> 4, rl = lane & 15;
        f16x8 af[4];
        #pragma unroll
        for (int rt = 0; rt < 4; ++rt)
            af[rt] = *reinterpret_cast<const f16x8*>(&Atile[(kc * 64 + rt * 16 + rl) * 8]);
        #pragma unroll
        for (int nt = 0; nt < 4; ++nt) {
            const int col = wave * 64 + nt * 16 + rl;
            f16x8 bf = *reinterpret_cast<const f16x8*>(&W[col * HIDDEN + k0 + kc * 8]);
            #pragma unroll
            for (int rt = 0; rt < 4; ++rt)
                acc[rt][nt] = MFMA16(af[rt], bf, acc[rt][nt]);
        }
        __syncthreads();
    }

    const int rl = lane & 15, rg = lane >> 4;
    #pragma unroll
    for (int rt = 0; rt < 4; ++rt)
        #pragma unroll
        for (int i = 0; i < 4; ++i) {
            const int r = rt * 16 + rg * 4 + i;
            if (e0 + r >= EPT) continue;
            const int tgt = s_tgt[r];
            #pragma unroll
            for (int nt = 0; nt < 4; ++nt) {
                const int col = wave * 64 + nt * 16 + rl;
                float v = acc[rt][nt][i] + bm[col];
                atomicAdd(&incoming[(size_t)tgt * HIDDEN + col], v);
            }
        }
}

// ---------------- fused GRU cell ----------------
// tile 32 rows x 256 cols; K = 512 over [incoming | h]; 4 quantities s_r,s_z,i_n,h_n
__global__ __launch_bounds__(256) void k_gru(
    const float* __restrict__ incoming,
    const float* __restrict__ h,            // fp32 h_old (read in epilogue only)
    const half_t* __restrict__ h16,
    const half_t* __restrict__ Wih16,       // (2,768,256)
    const half_t* __restrict__ Whh16,
    const float* __restrict__ b_ih,         // (2,768)
    const float* __restrict__ b_hh,
    float* __restrict__ hout,
    half_t* __restrict__ h16out,
    int layer)
{
    __shared__ half_t Atile[4 * 32 * 8];    // [kchunk][row 32][8]
    const int tid  = threadIdx.x;
    const int lane = tid & 63;
    const int wave = tid >> 6;
    const int n0   = blockIdx.x * 32;

    const half_t* Wih = Wih16 + (size_t)layer * 768 * HIDDEN;
    const half_t* Whh = Whh16 + (size_t)layer * 768 * HIDDEN;
    const float*  bi  = b_ih + (size_t)layer * 768;
    const float*  bh  = b_hh + (size_t)layer * 768;

    f32x4 acc_r[2][4] = {}, acc_z[2][4] = {}, acc_in[2][4] = {}, acc_hn[2][4] = {};

    for (int ks = 0; ks < 16; ++ks) {
        const int k0 = ks * 32;
        if (tid < 128) {
            const int c = tid >> 5, r = tid & 31;
            const int node = n0 + r;
            f16x8 hv = {};
            if (node < N_NODES) {
                const int kk = k0 + c * 8;
                if (kk < HIDDEN) {
                    const float4* s4 = reinterpret_cast<const float4*>(incoming + (size_t)node * HIDDEN + kk);
                    float4 a0 = s4[0], a1 = s4[1];
                    hv[0]=(half_t)a0.x; hv[1]=(half_t)a0.y; hv[2]=(half_t)a0.z; hv[3]=(half_t)a0.w;
                    hv[4]=(half_t)a1.x; hv[5]=(half_t)a1.y; hv[6]=(half_t)a1.z; hv[7]=(half_t)a1.w;
                } else {
                    hv = *reinterpret_cast<const f16x8*>(&h16[(size_t)node * HIDDEN + (kk - HIDDEN)]);
                }
            }
            *reinterpret_cast<f16x8*>(&Atile[(c * 32 + r) * 8]) = hv;
        }
        __syncthreads();
        const int kc = lane >> 4, rl = lane & 15;
        f16x8 af[2];
        #pragma unroll
        for (int rt = 0; rt < 2; ++rt)
            af[rt] = *reinterpret_cast<const f16x8*>(&Atile[(kc * 32 + rt * 16 + rl) * 8]);
        const bool first = (k0 < HIDDEN);
        const half_t* Wk = first ? Wih : Whh;
        const int kk = (first ? k0 : (k0 - HIDDEN)) + kc * 8;
        #pragma unroll
        for (int nt = 0; nt < 4; ++nt) {
            const int col = wave * 64 + nt * 16 + rl;
            f16x8 b_r = *reinterpret_cast<const f16x8*>(&Wk[(size_t)(col      ) * HIDDEN + kk]);
            f16x8 b_z = *reinterpret_cast<const f16x8*>(&Wk[(size_t)(col + 256) * HIDDEN + kk]);
            f16x8 b_3 = *reinterpret_cast<const f16x8*>(&Wk[(size_t)(col + 512) * HIDDEN + kk]);
            #pragma unroll
            for (int rt = 0; rt < 2; ++rt) {
                acc_r[rt][nt] = MFMA16(af[rt], b_r, acc_r[rt][nt]);
                acc_z[rt][nt] = MFMA16(af[rt], b_z, acc_z[rt][nt]);
                if (first) acc_in[rt][nt] = MFMA16(af[rt], b_3, acc_in[rt][nt]);
                else       acc_hn[rt][nt] = MFMA16(af[rt], b_3, acc_hn[rt][nt]);
            }
        }
        __syncthreads();
    }

    const int rl = lane & 15, rg = lane >> 4;
    #pragma unroll
    for (int rt = 0; rt < 2; ++rt)
        #pragma unroll
        for (int i = 0; i < 4; ++i) {
            const int row = n0 + rt * 16 + rg * 4 + i;
            if (row >= N_NODES) continue;
            #pragma unroll
            for (int nt = 0; nt < 4; ++nt) {
                const int col = wave * 64 + nt * 16 + rl;
                float sr  = acc_r [rt][nt][i] + bi[col]       + bh[col];
                float sz  = acc_z [rt][nt][i] + bi[256 + col] + bh[256 + col];
                float xin = acc_in[rt][nt][i] + bi[512 + col];
                float xhn = acc_hn[rt][nt][i] + bh[512 + col];
                float r = 1.f / (1.f + __expf(-sr));
                float z = 1.f / (1.f + __expf(-sz));
                float a = xin + r * xhn;
                float e2 = __expf(2.f * a);
                float n = (e2 - 1.f) / (e2 + 1.f);
                float hold = h[(size_t)row * HIDDEN + col];
                float hv = (1.f - z) * n + z * hold;
                hout[(size_t)row * HIDDEN + col]   = hv;
                h16out[(size_t)row * HIDDEN + col] = (half_t)hv;
            }
        }
}

// ---------------- launcher ----------------
extern "C" void kernel_launch(void* const* d_in, const int* in_sizes, int n_in,
                              void* d_out, int out_size, void* d_ws, size_t ws_size,
                              hipStream_t stream) {
    const float* x      = (const float*)d_in[0];
    const float* annot  = (const float*)d_in[1];
    const int*   edges  = (const int*)  d_in[2];
    const float* W_hid  = (const float*)d_in[3];
    const float* b_hid  = (const float*)d_in[4];
    const float* W_msg  = (const float*)d_in[5];
    const float* b_msg  = (const float*)d_in[6];
    const float* W_ih   = (const float*)d_in[7];
    const float* W_hh   = (const float*)d_in[8];
    const float* b_ih   = (const float*)d_in[9];
    const float* b_hh   = (const float*)d_in[10];

    char* ws = (char*)d_ws;
    const size_t HB = (size_t)N_NODES * HIDDEN * 4;      // 51,200,000
    float*  h        = (float*) (ws + 0);
    float*  incoming = (float*) (ws + HB);
    half_t* h16      = (half_t*)(ws + 2 * HB);
    char*   wbase    = ws + 2 * HB + HB / 2;             // 128,000,000
    half_t* Whid16   = (half_t*)(wbase);                              // 73728
    half_t* Wmsg16   = (half_t*)(wbase + 256 * 1024);                 // 524288
    half_t* Wih16    = (half_t*)(wbase + 256 * 1024 + 2048 * 1024);   // 393216
    half_t* Whh16    = (half_t*)(wbase + 256 * 1024 + 3072 * 1024);   // 393216

    k_cvt<<<dim3((73728  + 255) / 256), 256, 0, stream>>>(W_hid, Whid16, 73728);
    k_cvt<<<dim3((524288 + 255) / 256), 256, 0, stream>>>(W_msg, Wmsg16, 524288);
    k_cvt<<<dim3((393216 + 255) / 256), 256, 0, stream>>>(W_ih,  Wih16,  393216);
    k_cvt<<<dim3((393216 + 255) / 256), 256, 0, stream>>>(W_hh,  Whh16,  393216);

    k_init<<<dim3((N_NODES + 63) / 64), 256, 0, stream>>>(x, annot, Whid16, b_hid, h, h16);

    for (int layer = 0; layer < 2; ++layer)
        for (int it = 0; it < 3; ++it) {
            hipMemsetAsync(incoming, 0, HB, stream);
            k_msgs<<<dim3((EPT + 63) / 64, NTYPES), 256, 0, stream>>>(
                h16, edges, Wmsg16, b_msg, incoming, layer);
            const bool last = (layer == 1 && it == 2);
            k_gru<<<dim3((N_NODES + 31) / 32), 256, 0, stream>>>(
                incoming, h, h16, Wih16, Whh16, b_ih, b_hh,
                last ? (float*)d_out : h, h16, layer);
        }
}

// Round 2
// 2367.996 us; speedup vs baseline: 1.5367x; 1.5367x over previous
//
#include <hip/hip_runtime.h>

#define N_NODES 50000
#define HIDDEN  256
#define ANNOT   32
#define NTYPES  4
#define EPT     75000
#define CAP     16   // max in-degree per (type,node); P(deg>16) ~ 1e-14 at lambda=1.5

typedef __attribute__((ext_vector_type(4))) float    f32x4;
typedef __attribute__((ext_vector_type(8))) _Float16 f16x8;
typedef __attribute__((ext_vector_type(4))) _Float16 f16x4;
typedef _Float16 half_t;

#define MFMA16(a,b,c) __builtin_amdgcn_mfma_f32_16x16x32_f16((a),(b),(c),0,0,0)

// ---------------- weight fp32 -> fp16 convert ----------------
__global__ void k_cvt(const float* __restrict__ in, half_t* __restrict__ out, int n) {
    int i = blockIdx.x * blockDim.x + threadIdx.x;
    if (i < n) out[i] = (half_t)in[i];
}

// W_msg (2,4,256,256)[l][t][g][c] -> Wcat (2,256,4,256)[l][g][t][c]
__global__ void k_cvt_wcat(const float* __restrict__ in, half_t* __restrict__ out) {
    int i = blockIdx.x * blockDim.x + threadIdx.x;
    if (i >= 2 * NTYPES * 256 * 256) return;
    const int c = i & 255, t = (i >> 8) & 3, g = (i >> 10) & 255, l = i >> 18;
    out[i] = (half_t)in[(((size_t)(l * NTYPES + t) * 256 + g) * 256) + c];
}

// ---------------- CSR-ish build: per (type,target) source list ----------------
__global__ void k_csr(const int* __restrict__ edges, int* __restrict__ cnt,
                      int* __restrict__ elist) {
    int i = blockIdx.x * blockDim.x + threadIdx.x;
    if (i >= NTYPES * EPT) return;
    int2 st = *reinterpret_cast<const int2*>(&edges[(size_t)i * 2]);
    const int t = i / EPT;
    const int slot = t * N_NODES + st.y;
    int pos = atomicAdd(&cnt[slot], 1);
    if (pos < CAP) elist[(size_t)slot * CAP + pos] = st.x;
}

__global__ void k_cntf(const int* __restrict__ cnt, float4* __restrict__ cntf) {
    int v = blockIdx.x * blockDim.x + threadIdx.x;
    if (v >= N_NODES) return;
    cntf[v] = make_float4((float)cnt[v], (float)cnt[N_NODES + v],
                          (float)cnt[2 * N_NODES + v], (float)cnt[3 * N_NODES + v]);
}

// ---------------- h0 = [x | annot] @ W_hid^T + b_hid ----------------
__global__ __launch_bounds__(256) void k_init(
    const float* __restrict__ x, const float* __restrict__ annot,
    const half_t* __restrict__ Whid16, const float* __restrict__ b_hid,
    float* __restrict__ h, half_t* __restrict__ h16)
{
    __shared__ half_t Atile[4 * 64 * 8];
    const int tid  = threadIdx.x;
    const int lane = tid & 63;
    const int wave = tid >> 6;
    const int n0   = blockIdx.x * 64;

    f32x4 acc[4][4] = {};

    for (int ks = 0; ks < 9; ++ks) {
        const int k0 = ks * 32;
        {
            const int c = tid >> 6, r = tid & 63;
            const int node = n0 + r;
            f16x8 hv = {};
            if (node < N_NODES) {
                const int kk = k0 + c * 8;
                const float* s = (kk < HIDDEN) ? (x + (size_t)node * HIDDEN + kk)
                                               : (annot + (size_t)node * ANNOT + (kk - HIDDEN));
                const float4* s4 = reinterpret_cast<const float4*>(s);
                float4 a0 = s4[0], a1 = s4[1];
                hv[0]=(half_t)a0.x; hv[1]=(half_t)a0.y; hv[2]=(half_t)a0.z; hv[3]=(half_t)a0.w;
                hv[4]=(half_t)a1.x; hv[5]=(half_t)a1.y; hv[6]=(half_t)a1.z; hv[7]=(half_t)a1.w;
            }
            *reinterpret_cast<f16x8*>(&Atile[(c * 64 + r) * 8]) = hv;
        }
        __syncthreads();
        const int kc = lane >> 4, rl = lane & 15;
        f16x8 af[4];
        #pragma unroll
        for (int rt = 0; rt < 4; ++rt)
            af[rt] = *reinterpret_cast<const f16x8*>(&Atile[(kc * 64 + rt * 16 + rl) * 8]);
        #pragma unroll
        for (int nt = 0; nt < 4; ++nt) {
            const int col = wave * 64 + nt * 16 + rl;
            f16x8 bf = *reinterpret_cast<const f16x8*>(&Whid16[col * 288 + k0 + kc * 8]);
            #pragma unroll
            for (int rt = 0; rt < 4; ++rt)
                acc[rt][nt] = MFMA16(af[rt], bf, acc[rt][nt]);
        }
        __syncthreads();
    }

    const int rl = lane & 15, rg = lane >> 4;
    #pragma unroll
    for (int rt = 0; rt < 4; ++rt)
        #pragma unroll
        for (int i = 0; i < 4; ++i) {
            const int row = n0 + rt * 16 + rg * 4 + i;
            if (row >= N_NODES) continue;
            #pragma unroll
            for (int nt = 0; nt < 4; ++nt) {
                const int col = wave * 64 + nt * 16 + rl;
                float v = acc[rt][nt][i] + b_hid[col];
                h[(size_t)row * HIDDEN + col]   = v;
                h16[(size_t)row * HIDDEN + col] = (half_t)v;
            }
        }
}

// ---------------- per-node neighbor aggregation: S[v][t*256+c] = sum h16[src][c] ----------------
// one wave per node; lane covers 4 cols
__global__ __launch_bounds__(256) void k_agg(
    const half_t* __restrict__ h16,
    const int* __restrict__ cnt, const int* __restrict__ elist,
    half_t* __restrict__ S, int row0, int rows)
{
    const int wave = threadIdx.x >> 6;
    const int lane = threadIdx.x & 63;
    const int lr   = blockIdx.x * 4 + wave;
    if (lr >= rows) return;
    const int v = row0 + lr;

    #pragma unroll
    for (int t = 0; t < NTYPES; ++t) {
        const int slot = t * N_NODES + v;
        int c = cnt[slot]; if (c > CAP) c = CAP;
        float s0 = 0.f, s1 = 0.f, s2 = 0.f, s3 = 0.f;
        const int* el = elist + (size_t)slot * CAP;
        for (int e = 0; e < c; ++e) {
            const int src = el[e];
            f16x4 hv = *reinterpret_cast<const f16x4*>(&h16[(size_t)src * HIDDEN + lane * 4]);
            s0 += (float)hv[0]; s1 += (float)hv[1]; s2 += (float)hv[2]; s3 += (float)hv[3];
        }
        f16x4 o; o[0]=(half_t)s0; o[1]=(half_t)s1; o[2]=(half_t)s2; o[3]=(half_t)s3;
        *reinterpret_cast<f16x4*>(&S[(size_t)lr * 1024 + t * 256 + lane * 4]) = o;
    }
}

// ---------------- incoming GEMM: inc16 = S @ Wcat^T + cnt-weighted bias ----------------
// tile 64 rows x 256 cols, K = 1024
__global__ __launch_bounds__(256) void k_inc(
    const half_t* __restrict__ S,
    const half_t* __restrict__ Wcat16,      // (2,256,4,256)
    const float* __restrict__ b_msg,        // (2,4,256)
    const float4* __restrict__ cntf,
    half_t* __restrict__ inc16,
    int layer, int row0, int rows)
{
    __shared__ half_t Atile[4 * 64 * 8];
    const int tid  = threadIdx.x;
    const int lane = tid & 63;
    const int wave = tid >> 6;
    const int r0   = blockIdx.x * 64;

    const half_t* W  = Wcat16 + (size_t)layer * 256 * 1024;
    const float*  bm = b_msg + (size_t)layer * NTYPES * 256;

    f32x4 acc[4][4] = {};

    for (int ks = 0; ks < 32; ++ks) {
        const int k0 = ks * 32;
        {
            const int c = tid >> 6, r = tid & 63;
            f16x8 hv = {};
            if (r0 + r < rows)
                hv = *reinterpret_cast<const f16x8*>(&S[(size_t)(r0 + r) * 1024 + k0 + c * 8]);
            *reinterpret_cast<f16x8*>(&Atile[(c * 64 + r) * 8]) = hv;
        }
        __syncthreads();
        const int kc = lane >> 4, rl = lane & 15;
        f16x8 af[4];
        #pragma unroll
        for (int rt = 0; rt < 4; ++rt)
            af[rt] = *reinterpret_cast<const f16x8*>(&Atile[(kc * 64 + rt * 16 + rl) * 8]);
        #pragma unroll
        for (int nt = 0; nt < 4; ++nt) {
            const int col = wave * 64 + nt * 16 + rl;
            f16x8 bf = *reinterpret_cast<const f16x8*>(&W[(size_t)col * 1024 + k0 + kc * 8]);
            #pragma unroll
            for (int rt = 0; rt < 4; ++rt)
                acc[rt][nt] = MFMA16(af[rt], bf, acc[rt][nt]);
        }
        __syncthreads();
    }

    const int rl = lane & 15, rg = lane >> 4;
    #pragma unroll
    for (int rt = 0; rt < 4; ++rt)
        #pragma unroll
        for (int i = 0; i < 4; ++i) {
            const int lr = r0 + rt * 16 + rg * 4 + i;
            if (lr >= rows) continue;
            const int row = row0 + lr;
            const float4 cf = cntf[row];
            #pragma unroll
            for (int nt = 0; nt < 4; ++nt) {
                const int col = wave * 64 + nt * 16 + rl;
                float v = acc[rt][nt][i]
                        + cf.x * bm[col] + cf.y * bm[256 + col]
                        + cf.z * bm[512 + col] + cf.w * bm[768 + col];
                inc16[(size_t)row * HIDDEN + col] = (half_t)v;
            }
        }
}

// ---------------- fused GRU cell: 64 rows x 256 cols, 8 waves ----------------
__global__ __launch_bounds__(512) void k_gru(
    const half_t* __restrict__ inc16,
    const float* __restrict__ h,
    const half_t* __restrict__ h16,
    const half_t* __restrict__ Wih16,       // (2,768,256)
    const half_t* __restrict__ Whh16,
    const float* __restrict__ b_ih,
    const float* __restrict__ b_hh,
    float* __restrict__ hout,
    half_t* __restrict__ h16out,
    int layer)
{
    __shared__ half_t Atile[4 * 64 * 8];
    const int tid  = threadIdx.x;
    const int lane = tid & 63;
    const int wave = tid >> 6;
    const int rh   = wave >> 2;     // row half: 0/1
    const int wc   = wave & 3;      // col quarter
    const int n0   = blockIdx.x * 64;

    const half_t* Wih = Wih16 + (size_t)layer * 768 * HIDDEN;
    const half_t* Whh = Whh16 + (size_t)layer * 768 * HIDDEN;
    const float*  bi  = b_ih + (size_t)layer * 768;
    const float*  bh  = b_hh + (size_t)layer * 768;

    f32x4 acc_r[2][4] = {}, acc_z[2][4] = {}, acc_in[2][4] = {}, acc_hn[2][4] = {};

    for (int ks = 0; ks < 16; ++ks) {
        const int k0 = ks * 32;
        if (tid < 256) {
            const int c = tid >> 6, r = tid & 63;
            const int node = n0 + r;
            f16x8 hv = {};
            if (node < N_NODES) {
                const int kk = k0 + c * 8;
                const half_t* s = (kk < HIDDEN) ? (inc16 + (size_t)node * HIDDEN + kk)
                                                : (h16 + (size_t)node * HIDDEN + (kk - HIDDEN));
                hv = *reinterpret_cast<const f16x8*>(s);
            }
            *reinterpret_cast<f16x8*>(&Atile[(c * 64 + r) * 8]) = hv;
        }
        __syncthreads();
        const int kc = lane >> 4, rl = lane & 15;
        f16x8 af[2];
        #pragma unroll
        for (int rt = 0; rt < 2; ++rt)
            af[rt] = *reinterpret_cast<const f16x8*>(&Atile[(kc * 64 + rh * 32 + rt * 16 + rl) * 8]);
        const bool first = (k0 < HIDDEN);
        const half_t* Wk = first ? Wih : Whh;
        const int kk = (first ? k0 : (k0 - HIDDEN)) + kc * 8;
        #pragma unroll
        for (int nt = 0; nt < 4; ++nt) {
            const int col = wc * 64 + nt * 16 + rl;
            f16x8 b_r = *reinterpret_cast<const f16x8*>(&Wk[(size_t)(col      ) * HIDDEN + kk]);
            f16x8 b_z = *reinterpret_cast<const f16x8*>(&Wk[(size_t)(col + 256) * HIDDEN + kk]);
            f16x8 b_3 = *reinterpret_cast<const f16x8*>(&Wk[(size_t)(col + 512) * HIDDEN + kk]);
            #pragma unroll
            for (int rt = 0; rt < 2; ++rt) {
                acc_r[rt][nt] = MFMA16(af[rt], b_r, acc_r[rt][nt]);
                acc_z[rt][nt] = MFMA16(af[rt], b_z, acc_z[rt][nt]);
                if (first) acc_in[rt][nt] = MFMA16(af[rt], b_3, acc_in[rt][nt]);
                else       acc_hn[rt][nt] = MFMA16(af[rt], b_3, acc_hn[rt][nt]);
            }
        }
        __syncthreads();
    }

    const int rl = lane & 15, rg = lane >> 4;
    #pragma unroll
    for (int rt = 0; rt < 2; ++rt)
        #pragma unroll
        for (int i = 0; i < 4; ++i) {
            const int row = n0 + rh * 32 + rt * 16 + rg * 4 + i;
            if (row >= N_NODES) continue;
            #pragma unroll
            for (int nt = 0; nt < 4; ++nt) {
                const int col = wc * 64 + nt * 16 + rl;
                float sr  = acc_r [rt][nt][i] + bi[col]       + bh[col];
                float sz  = acc_z [rt][nt][i] + bi[256 + col] + bh[256 + col];
                float xin = acc_in[rt][nt][i] + bi[512 + col];
                float xhn = acc_hn[rt][nt][i] + bh[512 + col];
                float r = 1.f / (1.f + __expf(-sr));
                float z = 1.f / (1.f + __expf(-sz));
                float a = xin + r * xhn;
                float e2 = __expf(2.f * a);
                float n = (e2 - 1.f) / (e2 + 1.f);
                float hold = h[(size_t)row * HIDDEN + col];
                float hv = (1.f - z) * n + z * hold;
                hout[(size_t)row * HIDDEN + col]   = hv;
                h16out[(size_t)row * HIDDEN + col] = (half_t)hv;
            }
        }
}

// ---------------- launcher ----------------
extern "C" void kernel_launch(void* const* d_in, const int* in_sizes, int n_in,
                              void* d_out, int out_size, void* d_ws, size_t ws_size,
                              hipStream_t stream) {
    const float* x      = (const float*)d_in[0];
    const float* annot  = (const float*)d_in[1];
    const int*   edges  = (const int*)  d_in[2];
    const float* W_hid  = (const float*)d_in[3];
    const float* b_hid  = (const float*)d_in[4];
    const float* W_msg  = (const float*)d_in[5];
    const float* b_msg  = (const float*)d_in[6];
    const float* W_ih   = (const float*)d_in[7];
    const float* W_hh   = (const float*)d_in[8];
    const float* b_ih   = (const float*)d_in[9];
    const float* b_hh   = (const float*)d_in[10];

    char* ws = (char*)d_ws;
    size_t off = 0;
    auto alloc = [&](size_t bytes) -> char* {
        char* p = ws + off;
        off = (off + bytes + 255) & ~(size_t)255;
        return p;
    };
    float*  h      = (float*) alloc((size_t)N_NODES * HIDDEN * 4);
    half_t* h16    = (half_t*)alloc((size_t)N_NODES * HIDDEN * 2);
    half_t* inc16  = (half_t*)alloc((size_t)N_NODES * HIDDEN * 2);
    int*    elist  = (int*)   alloc((size_t)NTYPES * N_NODES * CAP * 4);
    int*    cnt    = (int*)   alloc((size_t)NTYPES * N_NODES * 4);
    float4* cntf   = (float4*)alloc((size_t)N_NODES * 16);
    half_t* Whid16 = (half_t*)alloc((size_t)HIDDEN * (HIDDEN + ANNOT) * 2);
    half_t* Wcat16 = (half_t*)alloc((size_t)2 * 256 * 1024 * 2);
    half_t* Wih16  = (half_t*)alloc((size_t)2 * 768 * 256 * 2);
    half_t* Whh16  = (half_t*)alloc((size_t)2 * 768 * 256 * 2);
    // S chunk takes the rest
    half_t* S = (half_t*)(ws + off);
    size_t s_rows_cap = (ws_size > off) ? (ws_size - off) / ((size_t)1024 * 2) : 0;
    int s_rows = (int)((s_rows_cap / 64) * 64);
    if (s_rows > N_NODES) s_rows = ((N_NODES + 63) / 64) * 64;
    if (s_rows < 64) s_rows = 64;   // ws too small would have failed round 1 anyway

    // one-time precompute
    hipMemsetAsync(cnt, 0, (size_t)NTYPES * N_NODES * 4, stream);
    k_csr <<<dim3((NTYPES * EPT + 255) / 256), 256, 0, stream>>>(edges, cnt, elist);
    k_cntf<<<dim3((N_NODES + 255) / 256), 256, 0, stream>>>(cnt, cntf);
    k_cvt <<<dim3((73728  + 255) / 256), 256, 0, stream>>>(W_hid, Whid16, 73728);
    k_cvt_wcat<<<dim3((524288 + 255) / 256), 256, 0, stream>>>(W_msg, Wcat16);
    k_cvt <<<dim3((393216 + 255) / 256), 256, 0, stream>>>(W_ih,  Wih16,  393216);
    k_cvt <<<dim3((393216 + 255) / 256), 256, 0, stream>>>(W_hh,  Whh16,  393216);

    k_init<<<dim3((N_NODES + 63) / 64), 256, 0, stream>>>(x, annot, Whid16, b_hid, h, h16);

    for (int layer = 0; layer < 2; ++layer)
        for (int it = 0; it < 3; ++it) {
            for (int row0 = 0; row0 < N_NODES; row0 += s_rows) {
                const int rows = (N_NODES - row0 < s_rows) ? (N_NODES - row0) : s_rows;
                k_agg<<<dim3((rows + 3) / 4), 256, 0, stream>>>(h16, cnt, elist, S, row0, rows);
                k_inc<<<dim3((rows + 63) / 64), 256, 0, stream>>>(
                    S, Wcat16, b_msg, cntf, inc16, layer, row0, rows);
            }
            const bool last = (layer == 1 && it == 2);
            k_gru<<<dim3((N_NODES + 63) / 64), 512, 0, stream>>>(
                inc16, h, h16, Wih16, Whh16, b_ih, b_hh,
                last ? (float*)d_out : h, h16, layer);
        }
}

// Round 3
// 2226.430 us; speedup vs baseline: 1.6344x; 1.0636x over previous
//
#include <hip/hip_runtime.h>

#define N_NODES 50000
#define HIDDEN  256
#define ANNOT   32
#define NTYPES  4
#define EPT     75000
#define CAP     16   // max in-degree per (type,node); Poisson lambda=1.5 -> P(>16) ~ 0

typedef __attribute__((ext_vector_type(4))) float    f32x4;
typedef __attribute__((ext_vector_type(8))) _Float16 f16x8;
typedef __attribute__((ext_vector_type(4))) _Float16 f16x4;
typedef _Float16 half_t;

#define MFMA16(a,b,c) __builtin_amdgcn_mfma_f32_16x16x32_f16((a),(b),(c),0,0,0)

__device__ __forceinline__ void gload16(const void* g, void* l) {
    __builtin_amdgcn_global_load_lds((const __attribute__((address_space(1))) void*)g,
                                     (__attribute__((address_space(3))) void*)l, 16, 0, 0);
}

// ---------------- weight fp32 -> fp16 convert (flat) ----------------
__global__ void k_cvt(const float* __restrict__ in, half_t* __restrict__ out, int n) {
    int i = blockIdx.x * blockDim.x + threadIdx.x;
    if (i < n) out[i] = (half_t)in[i];
}

// ---------------- CSR build: per (type,target) source list ----------------
__global__ void k_csr(const int* __restrict__ edges, int* __restrict__ cnt,
                      int* __restrict__ elist) {
    int i = blockIdx.x * blockDim.x + threadIdx.x;
    if (i >= NTYPES * EPT) return;
    int2 st = *reinterpret_cast<const int2*>(&edges[(size_t)i * 2]);
    const int t = i / EPT;
    const int slot = t * N_NODES + st.y;
    int pos = atomicAdd(&cnt[slot], 1);
    if (pos < CAP) elist[(size_t)slot * CAP + pos] = st.x;
}

// ---------------- h0 = [x | annot] @ W_hid^T + b_hid  (runs once) ----------------
// hx layout: per node 512 halfs = [h16(256) | inc16(256)]
__global__ __launch_bounds__(256) void k_init(
    const float* __restrict__ x, const float* __restrict__ annot,
    const half_t* __restrict__ Whid16, const float* __restrict__ b_hid,
    half_t* __restrict__ hx)
{
    __shared__ __align__(16) half_t Atile[4 * 64 * 8];
    const int tid  = threadIdx.x;
    const int lane = tid & 63;
    const int wave = tid >> 6;
    const int n0   = blockIdx.x * 64;

    f32x4 acc[4][4] = {};

    for (int ks = 0; ks < 9; ++ks) {
        const int k0 = ks * 32;
        {
            const int c = tid >> 6, r = tid & 63;
            const int node = n0 + r;
            f16x8 hv = {};
            if (node < N_NODES) {
                const int kk = k0 + c * 8;
                const float* s = (kk < HIDDEN) ? (x + (size_t)node * HIDDEN + kk)
                                               : (annot + (size_t)node * ANNOT + (kk - HIDDEN));
                const float4* s4 = reinterpret_cast<const float4*>(s);
                float4 a0 = s4[0], a1 = s4[1];
                hv[0]=(half_t)a0.x; hv[1]=(half_t)a0.y; hv[2]=(half_t)a0.z; hv[3]=(half_t)a0.w;
                hv[4]=(half_t)a1.x; hv[5]=(half_t)a1.y; hv[6]=(half_t)a1.z; hv[7]=(half_t)a1.w;
            }
            *reinterpret_cast<f16x8*>(&Atile[(c * 64 + r) * 8]) = hv;
        }
        __syncthreads();
        const int kc = lane >> 4, rl = lane & 15;
        f16x8 af[4];
        #pragma unroll
        for (int rt = 0; rt < 4; ++rt)
            af[rt] = *reinterpret_cast<const f16x8*>(&Atile[(kc * 64 + rt * 16 + rl) * 8]);
        #pragma unroll
        for (int nt = 0; nt < 4; ++nt) {
            const int col = wave * 64 + nt * 16 + rl;
            f16x8 bf = *reinterpret_cast<const f16x8*>(&Whid16[col * 288 + k0 + kc * 8]);
            #pragma unroll
            for (int rt = 0; rt < 4; ++rt)
                acc[rt][nt] = MFMA16(af[rt], bf, acc[rt][nt]);
        }
        __syncthreads();
    }

    const int rl = lane & 15, rg = lane >> 4;
    #pragma unroll
    for (int rt = 0; rt < 4; ++rt)
        #pragma unroll
        for (int i = 0; i < 4; ++i) {
            const int row = n0 + rt * 16 + rg * 4 + i;
            if (row >= N_NODES) continue;
            #pragma unroll
            for (int nt = 0; nt < 4; ++nt) {
                const int col = wave * 64 + nt * 16 + rl;
                hx[(size_t)row * 512 + col] = (half_t)(acc[rt][nt][i] + b_hid[col]);
            }
        }
}

// ---------------- k_y: Y = h16 @ Wmsg_stack^T  (M=50000, N=1024, K=256) ----------------
// tile 64 rows x 256 cols, grid (782, 4); 256 thr / 4 waves; stage full A once.
__global__ __launch_bounds__(256) void k_y(
    const half_t* __restrict__ hx,
    const half_t* __restrict__ Wmsg16,      // (2, 1024, 256)
    half_t* __restrict__ Y, int layer)
{
    __shared__ __align__(16) half_t As[32 * 64 * 8];     // 32 KB: [slot(32)][row(64)][8]
    __shared__ __align__(16) half_t OutT[64 * 264];      // 33.8 KB padded transpose buf
    const int t    = threadIdx.x;
    const int lane = t & 63;
    const int w    = t >> 6;
    const int n0   = blockIdx.x * 64;
    const int yb   = blockIdx.y;

    #pragma unroll
    for (int p = 0; p < 8; ++p) {
        const int chunk = p * 256 + t;
        const int slot = chunk >> 6, row = chunk & 63;
        int node = n0 + row; if (node >= N_NODES) node = N_NODES - 1;
        gload16(hx + (size_t)node * 512 + slot * 8, As + (size_t)chunk * 8);
    }
    __syncthreads();

    const half_t* W = Wmsg16 + (size_t)layer * 1024 * 256;
    const int kc = lane >> 4, rl = lane & 15;
    f32x4 acc[4][4] = {};

    #pragma unroll 2
    for (int ks = 0; ks < 8; ++ks) {
        f16x8 af[4];
        #pragma unroll
        for (int rt = 0; rt < 4; ++rt)
            af[rt] = *reinterpret_cast<const f16x8*>(&As[((ks * 4 + kc) * 64 + rt * 16 + rl) * 8]);
        const int kb = ks * 32 + kc * 8;
        #pragma unroll
        for (int nt = 0; nt < 4; ++nt) {
            const int col = yb * 256 + w * 64 + nt * 16 + rl;
            f16x8 bf = *reinterpret_cast<const f16x8*>(&W[(size_t)col * 256 + kb]);
            #pragma unroll
            for (int rt = 0; rt < 4; ++rt)
                acc[rt][nt] = MFMA16(af[rt], bf, acc[rt][nt]);
        }
    }

    // transpose epilogue
    const int rg = lane >> 4;
    #pragma unroll
    for (int rt = 0; rt < 4; ++rt)
        #pragma unroll
        for (int i = 0; i < 4; ++i) {
            const int row_l = rt * 16 + rg * 4 + i;
            #pragma unroll
            for (int nt = 0; nt < 4; ++nt) {
                const int col_l = w * 64 + nt * 16 + rl;
                OutT[row_l * 264 + col_l] = (half_t)acc[rt][nt][i];
            }
        }
    __syncthreads();
    #pragma unroll
    for (int j = 0; j < 8; ++j) {
        const int row = j * 8 + (t >> 5), colb = t & 31;
        if (n0 + row < N_NODES) {
            f16x8 v = *reinterpret_cast<const f16x8*>(&OutT[row * 264 + colb * 8]);
            *reinterpret_cast<f16x8*>(&Y[(size_t)(n0 + row) * 1024 + yb * 256 + colb * 8]) = v;
        }
    }
}

// ---------------- k_gather: inc[v] = sum_t sum_e Y[src][t] + cnt_t * b_t ----------------
__global__ __launch_bounds__(256) void k_gather(
    const half_t* __restrict__ Y, const int* __restrict__ cnt,
    const int* __restrict__ elist, const float* __restrict__ b_msg,
    half_t* __restrict__ hx, int layer)
{
    const int wave = threadIdx.x >> 6, lane = threadIdx.x & 63;
    const int v = blockIdx.x * 4 + wave;
    if (v >= N_NODES) return;
    float s0 = 0.f, s1 = 0.f, s2 = 0.f, s3 = 0.f;
    const float4* bm = reinterpret_cast<const float4*>(b_msg + (size_t)layer * NTYPES * 256);
    #pragma unroll
    for (int t = 0; t < NTYPES; ++t) {
        const int slot = t * N_NODES + v;
        const int c = cnt[slot];
        const int cc = c < CAP ? c : CAP;
        const int* el = elist + (size_t)slot * CAP;
        for (int e = 0; e < cc; ++e) {
            const int src = el[e];
            f16x4 y = *reinterpret_cast<const f16x4*>(&Y[(size_t)src * 1024 + t * 256 + lane * 4]);
            s0 += (float)y[0]; s1 += (float)y[1]; s2 += (float)y[2]; s3 += (float)y[3];
        }
        float4 b = bm[t * 64 + lane];
        const float fc = (float)c;
        s0 += fc * b.x; s1 += fc * b.y; s2 += fc * b.z; s3 += fc * b.w;
    }
    f16x4 o; o[0] = (half_t)s0; o[1] = (half_t)s1; o[2] = (half_t)s2; o[3] = (half_t)s3;
    *reinterpret_cast<f16x4*>(&hx[(size_t)v * 512 + 256 + lane * 4]) = o;
}

// ---------------- k_gru: monolithic fused GRU (A = [h16 | inc], K = 512) ----------------
// 64 rows x 768 gate-cols; 512 thr / 8 waves (2 row-halves x 4 col-quarters)
__global__ __launch_bounds__(512) void k_gru(
    half_t* __restrict__ hx,
    const half_t* __restrict__ Wih16, const half_t* __restrict__ Whh16,
    const float* __restrict__ b_ih, const float* __restrict__ b_hh,
    int layer, int last)
{
    __shared__ __align__(16) half_t As[64 * 512];   // 64 KB: [slot(64)][row(64)][8]; reused as OutT
    const int t    = threadIdx.x;
    const int lane = t & 63;
    const int rh   = (t >> 6) >> 2;
    const int wc   = (t >> 6) & 3;
    const int n0   = blockIdx.x * 64;

    // stage full A tile (64 rows x 1 KB each, contiguous rows of hx)
    #pragma unroll
    for (int p = 0; p < 8; ++p) {
        const int chunk = p * 512 + t;
        const int slot = chunk >> 6, row = chunk & 63;
        int node = n0 + row; if (node >= N_NODES) node = N_NODES - 1;
        gload16(hx + (size_t)node * 512 + slot * 8, As + (size_t)chunk * 8);
    }
    __syncthreads();

    const half_t* Wih = Wih16 + (size_t)layer * 768 * 256;
    const half_t* Whh = Whh16 + (size_t)layer * 768 * 256;
    const float*  bi  = b_ih + layer * 768;
    const float*  bh  = b_hh + layer * 768;

    const int kc = lane >> 4, rl = lane & 15;
    f32x4 acc_r[2][4] = {}, acc_z[2][4] = {}, acc_in[2][4] = {}, acc_hn[2][4] = {};

    // h-part: k 0..255 (slots 0..31) against Whh
    #pragma unroll 2
    for (int ks = 0; ks < 8; ++ks) {
        f16x8 af[2];
        #pragma unroll
        for (int rt = 0; rt < 2; ++rt)
            af[rt] = *reinterpret_cast<const f16x8*>(&As[((ks * 4 + kc) * 64 + rh * 32 + rt * 16 + rl) * 8]);
        const int kb = ks * 32 + kc * 8;
        #pragma unroll
        for (int nt = 0; nt < 4; ++nt) {
            const int col = wc * 64 + nt * 16 + rl;
            f16x8 b_r = *reinterpret_cast<const f16x8*>(&Whh[(size_t)(col      ) * 256 + kb]);
            f16x8 b_z = *reinterpret_cast<const f16x8*>(&Whh[(size_t)(col + 256) * 256 + kb]);
            f16x8 b_n = *reinterpret_cast<const f16x8*>(&Whh[(size_t)(col + 512) * 256 + kb]);
            #pragma unroll
            for (int rt = 0; rt < 2; ++rt) {
                acc_r [rt][nt] = MFMA16(af[rt], b_r, acc_r [rt][nt]);
                acc_z [rt][nt] = MFMA16(af[rt], b_z, acc_z [rt][nt]);
                acc_hn[rt][nt] = MFMA16(af[rt], b_n, acc_hn[rt][nt]);
            }
        }
    }
    // inc-part: k 256..511 (slots 32..63) against Wih
    #pragma unroll 2
    for (int ks = 0; ks < 8; ++ks) {
        f16x8 af[2];
        #pragma unroll
        for (int rt = 0; rt < 2; ++rt)
            af[rt] = *reinterpret_cast<const f16x8*>(&As[(((8 + ks) * 4 + kc) * 64 + rh * 32 + rt * 16 + rl) * 8]);
        const int kb = ks * 32 + kc * 8;
        #pragma unroll
        for (int nt = 0; nt < 4; ++nt) {
            const int col = wc * 64 + nt * 16 + rl;
            f16x8 b_r = *reinterpret_cast<const f16x8*>(&Wih[(size_t)(col      ) * 256 + kb]);
            f16x8 b_z = *reinterpret_cast<const f16x8*>(&Wih[(size_t)(col + 256) * 256 + kb]);
            f16x8 b_n = *reinterpret_cast<const f16x8*>(&Wih[(size_t)(col + 512) * 256 + kb]);
            #pragma unroll
            for (int rt = 0; rt < 2; ++rt) {
                acc_r [rt][nt] = MFMA16(af[rt], b_r, acc_r [rt][nt]);
                acc_z [rt][nt] = MFMA16(af[rt], b_z, acc_z [rt][nt]);
                acc_in[rt][nt] = MFMA16(af[rt], b_n, acc_in[rt][nt]);
            }
        }
    }
    __syncthreads();   // all As reads done (region reused as OutT below)

    // GRU epilogue: compute new h into acc_r
    const int rg = lane >> 4;
    #pragma unroll
    for (int rt = 0; rt < 2; ++rt)
        #pragma unroll
        for (int i = 0; i < 4; ++i) {
            const int row_l = rh * 32 + rt * 16 + rg * 4 + i;
            const int row = n0 + row_l;
            const bool ok = row < N_NODES;
            #pragma unroll
            for (int nt = 0; nt < 4; ++nt) {
                const int col = wc * 64 + nt * 16 + rl;
                float sr  = acc_r [rt][nt][i] + bi[col]       + bh[col];
                float sz  = acc_z [rt][nt][i] + bi[256 + col] + bh[256 + col];
                float xin = acc_in[rt][nt][i] + bi[512 + col];
                float xhn = acc_hn[rt][nt][i] + bh[512 + col];
                float r = 1.f / (1.f + __expf(-sr));
                float z = 1.f / (1.f + __expf(-sz));
                float a = xin + r * xhn;
                float e2 = __expf(2.f * a);
                float n = (e2 - 1.f) / (e2 + 1.f);
                float hold = ok ? (float)hx[(size_t)row * 512 + col] : 0.f;
                acc_r[rt][nt][i] = (1.f - z) * n + z * hold;
            }
        }

    if (!last) {
        // transpose to LDS, coalesced fp16 store into h16 half of hx
        #pragma unroll
        for (int rt = 0; rt < 2; ++rt)
            #pragma unroll
            for (int i = 0; i < 4; ++i) {
                const int row_l = rh * 32 + rt * 16 + rg * 4 + i;
                #pragma unroll
                for (int nt = 0; nt < 4; ++nt) {
                    const int col = wc * 64 + nt * 16 + rl;
                    As[row_l * 264 + col] = (half_t)acc_r[rt][nt][i];
                }
            }
        __syncthreads();
        #pragma unroll
        for (int j = 0; j < 4; ++j) {
            const int row = j * 16 + (t >> 5), colb = t & 31;
            if (n0 + row < N_NODES) {
                f16x8 v = *reinterpret_cast<const f16x8*>(&As[row * 264 + colb * 8]);
                *reinterpret_cast<f16x8*>(&hx[(size_t)(n0 + row) * 512 + colb * 8]) = v;
            }
        }
    } else {
        __syncthreads();   // all hold-reads complete before fp32 overwrites the region
        float* out = reinterpret_cast<float*>(hx);
        #pragma unroll
        for (int rt = 0; rt < 2; ++rt)
            #pragma unroll
            for (int i = 0; i < 4; ++i) {
                const int row = n0 + rh * 32 + rt * 16 + rg * 4 + i;
                if (row >= N_NODES) continue;
                #pragma unroll
                for (int nt = 0; nt < 4; ++nt) {
                    const int col = wc * 64 + nt * 16 + rl;
                    out[(size_t)row * 256 + col] = acc_r[rt][nt][i];
                }
            }
    }
}

// ---------------- launcher ----------------
extern "C" void kernel_launch(void* const* d_in, const int* in_sizes, int n_in,
                              void* d_out, int out_size, void* d_ws, size_t ws_size,
                              hipStream_t stream) {
    const float* x      = (const float*)d_in[0];
    const float* annot  = (const float*)d_in[1];
    const int*   edges  = (const int*)  d_in[2];
    const float* W_hid  = (const float*)d_in[3];
    const float* b_hid  = (const float*)d_in[4];
    const float* W_msg  = (const float*)d_in[5];
    const float* b_msg  = (const float*)d_in[6];
    const float* W_ih   = (const float*)d_in[7];
    const float* W_hh   = (const float*)d_in[8];
    const float* b_ih   = (const float*)d_in[9];
    const float* b_hh   = (const float*)d_in[10];

    // node state lives in d_out: per node 512 halfs = [h16 | inc16]; final step overwrites with fp32 out
    half_t* hx = (half_t*)d_out;

    char* ws = (char*)d_ws;
    size_t off = 0;
    auto alloc = [&](size_t bytes) -> char* {
        char* p = ws + off;
        off = (off + bytes + 255) & ~(size_t)255;
        return p;
    };
    half_t* Y      = (half_t*)alloc((size_t)N_NODES * 1024 * 2);          // 102.4 MB
    int*    elist  = (int*)   alloc((size_t)NTYPES * N_NODES * CAP * 4);  // 12.8 MB
    int*    cnt    = (int*)   alloc((size_t)NTYPES * N_NODES * 4);        // 0.8 MB
    half_t* Whid16 = (half_t*)alloc((size_t)256 * 288 * 2);
    half_t* Wmsg16 = (half_t*)alloc((size_t)2 * 1024 * 256 * 2);
    half_t* Wih16  = (half_t*)alloc((size_t)2 * 768 * 256 * 2);
    half_t* Whh16  = (half_t*)alloc((size_t)2 * 768 * 256 * 2);
    (void)ws_size;

    hipMemsetAsync(cnt, 0, (size_t)NTYPES * N_NODES * 4, stream);
    k_csr<<<dim3((NTYPES * EPT + 255) / 256), 256, 0, stream>>>(edges, cnt, elist);
    k_cvt<<<dim3((73728  + 255) / 256), 256, 0, stream>>>(W_hid, Whid16, 73728);
    k_cvt<<<dim3((524288 + 255) / 256), 256, 0, stream>>>(W_msg, Wmsg16, 524288);
    k_cvt<<<dim3((393216 + 255) / 256), 256, 0, stream>>>(W_ih,  Wih16,  393216);
    k_cvt<<<dim3((393216 + 255) / 256), 256, 0, stream>>>(W_hh,  Whh16,  393216);

    const int NB = (N_NODES + 63) / 64;   // 782
    k_init<<<dim3(NB), 256, 0, stream>>>(x, annot, Whid16, b_hid, hx);

    for (int layer = 0; layer < 2; ++layer)
        for (int it = 0; it < 3; ++it) {
            k_y<<<dim3(NB, 4), 256, 0, stream>>>(hx, Wmsg16, Y, layer);
            k_gather<<<dim3((N_NODES + 3) / 4), 256, 0, stream>>>(Y, cnt, elist, b_msg, hx, layer);
            const int last = (layer == 1 && it == 2) ? 1 : 0;
            k_gru<<<dim3(NB), 512, 0, stream>>>(hx, Wih16, Whh16, b_ih, b_hh, layer, last);
        }
}

// Round 4
// 1147.946 us; speedup vs baseline: 3.1699x; 1.9395x over previous
//
#include <hip/hip_runtime.h>

#define N_NODES 50000
#define HIDDEN  256
#define ANNOT   32
#define NTYPES  4
#define EPT     75000
#define CAP     16   // max in-degree per (type,node); Poisson lambda=1.5 -> P(>16) ~ 0

typedef __attribute__((ext_vector_type(4))) float    f32x4;
typedef __attribute__((ext_vector_type(8))) _Float16 f16x8;
typedef __attribute__((ext_vector_type(4))) _Float16 f16x4;
typedef _Float16 half_t;

#define MFMA16(a,b,c) __builtin_amdgcn_mfma_f32_16x16x32_f16((a),(b),(c),0,0,0)

__device__ __forceinline__ void gload16(const void* g, void* l) {
    __builtin_amdgcn_global_load_lds((const __attribute__((address_space(1))) void*)g,
                                     (__attribute__((address_space(3))) void*)l, 16, 0, 0);
}

// ---------------- flat fp32 -> fp16 convert (W_hid only) ----------------
__global__ void k_cvt(const float* __restrict__ in, half_t* __restrict__ out, int n) {
    int i = blockIdx.x * blockDim.x + threadIdx.x;
    if (i < n) out[i] = (half_t)in[i];
}

// ---- GRU weights -> chunked LDS-image layout ----
// Wg[layer][chunk16][yb2][gate3][cl128][ksw4][e8]; K = [h(Whh) 0..255 | inc(Wih) 256..511]
__global__ void k_cvt_wg(const float* __restrict__ Wih, const float* __restrict__ Whh,
                         half_t* __restrict__ out) {
    int i = blockIdx.x * blockDim.x + threadIdx.x;
    if (i >= 786432) return;
    const int e = i & 7, ksw = (i >> 3) & 3, cl = (i >> 5) & 127;
    int r = i >> 12;
    const int g = r % 3; r /= 3;
    const int yb = r & 1; r >>= 1;
    const int chunk = r & 15;
    const int layer = r >> 4;
    const int kc = ksw ^ (cl & 3);
    const int k = chunk * 32 + kc * 8 + e;
    const int gcol = g * 256 + yb * 128 + cl;
    float v = (k < 256) ? Whh[((size_t)layer * 768 + gcol) * 256 + k]
                        : Wih[((size_t)layer * 768 + gcol) * 256 + (k - 256)];
    out[i] = (half_t)v;
}

// ---- message weights -> chunked layout: Wy[layer][chunk8][yb4][cl256][ksw4][e8] ----
__global__ void k_cvt_wy(const float* __restrict__ Wmsg, half_t* __restrict__ out) {
    int i = blockIdx.x * blockDim.x + threadIdx.x;
    if (i >= 524288) return;
    const int e = i & 7, ksw = (i >> 3) & 3, cl = (i >> 5) & 255;
    int r = i >> 13;
    const int yb = r & 3; r >>= 2;
    const int chunk = r & 7;
    const int layer = r >> 3;
    const int kc = ksw ^ (cl & 3);
    const int k = chunk * 32 + kc * 8 + e;
    const int col = yb * 256 + cl;
    out[i] = (half_t)Wmsg[(((size_t)layer * 4 + (col >> 8)) * 256 + (col & 255)) * 256 + k];
}

// ---------------- CSR build: per (type,target) source list ----------------
__global__ void k_csr(const int* __restrict__ edges, int* __restrict__ cnt,
                      int* __restrict__ elist) {
    int i = blockIdx.x * blockDim.x + threadIdx.x;
    if (i >= NTYPES * EPT) return;
    int2 st = *reinterpret_cast<const int2*>(&edges[(size_t)i * 2]);
    const int t = i / EPT;
    const int slot = t * N_NODES + st.y;
    int pos = atomicAdd(&cnt[slot], 1);
    if (pos < CAP) elist[(size_t)slot * CAP + pos] = st.x;
}

// ---------------- h0 = [x | annot] @ W_hid^T + b_hid  (runs once) ----------------
__global__ __launch_bounds__(256) void k_init(
    const float* __restrict__ x, const float* __restrict__ annot,
    const half_t* __restrict__ Whid16, const float* __restrict__ b_hid,
    half_t* __restrict__ hx)
{
    __shared__ __align__(16) half_t Atile[4 * 64 * 8];
    const int tid  = threadIdx.x;
    const int lane = tid & 63;
    const int wave = tid >> 6;
    const int n0   = blockIdx.x * 64;

    f32x4 acc[4][4] = {};

    for (int ks = 0; ks < 9; ++ks) {
        const int k0 = ks * 32;
        {
            const int c = tid >> 6, r = tid & 63;
            const int node = n0 + r;
            f16x8 hv = {};
            if (node < N_NODES) {
                const int kk = k0 + c * 8;
                const float* s = (kk < HIDDEN) ? (x + (size_t)node * HIDDEN + kk)
                                               : (annot + (size_t)node * ANNOT + (kk - HIDDEN));
                const float4* s4 = reinterpret_cast<const float4*>(s);
                float4 a0 = s4[0], a1 = s4[1];
                hv[0]=(half_t)a0.x; hv[1]=(half_t)a0.y; hv[2]=(half_t)a0.z; hv[3]=(half_t)a0.w;
                hv[4]=(half_t)a1.x; hv[5]=(half_t)a1.y; hv[6]=(half_t)a1.z; hv[7]=(half_t)a1.w;
            }
            *reinterpret_cast<f16x8*>(&Atile[(c * 64 + r) * 8]) = hv;
        }
        __syncthreads();
        const int kc = lane >> 4, rl = lane & 15;
        f16x8 af[4];
        #pragma unroll
        for (int rt = 0; rt < 4; ++rt)
            af[rt] = *reinterpret_cast<const f16x8*>(&Atile[(kc * 64 + rt * 16 + rl) * 8]);
        #pragma unroll
        for (int nt = 0; nt < 4; ++nt) {
            const int col = wave * 64 + nt * 16 + rl;
            f16x8 bf = *reinterpret_cast<const f16x8*>(&Whid16[col * 288 + k0 + kc * 8]);
            #pragma unroll
            for (int rt = 0; rt < 4; ++rt)
                acc[rt][nt] = MFMA16(af[rt], bf, acc[rt][nt]);
        }
        __syncthreads();
    }

    const int rl = lane & 15, rg = lane >> 4;
    #pragma unroll
    for (int rt = 0; rt < 4; ++rt)
        #pragma unroll
        for (int i = 0; i < 4; ++i) {
            const int row = n0 + rt * 16 + rg * 4 + i;
            if (row >= N_NODES) continue;
            #pragma unroll
            for (int nt = 0; nt < 4; ++nt) {
                const int col = wave * 64 + nt * 16 + rl;
                hx[(size_t)row * 512 + col] = (half_t)(acc[rt][nt][i] + b_hid[col]);
            }
        }
}

// ---------------- k_y2: Y[:, yb*256..] = h16 @ Wy^T ; B staged in LDS per K-chunk ----------------
// grid (782, 4), 512 thr / 8 waves (rh2 x wc4); BK=32, 8 chunks, dbuf
__global__ __launch_bounds__(512) void k_y2(
    const half_t* __restrict__ hxin, const half_t* __restrict__ Wy,
    half_t* __restrict__ Y, int layer)
{
    __shared__ __align__(16) half_t lds[2 * 10240];   // per buf: B 8192 + A 2048 halfs
    const int t = threadIdx.x, lane = t & 63;
    const int rh = (t >> 6) >> 2, wc = (t >> 6) & 3;
    const int n0 = blockIdx.x * 64, yb = blockIdx.y;
    const int kc = lane >> 4, rl = lane & 15;
    const int sw = kc ^ (rl & 3);

    f32x4 acc[2][4] = {};

    {   // stage chunk 0
        half_t* bB = lds; half_t* bA = lds + 8192;
        const half_t* Wc = Wy + (size_t)((layer * 8 + 0) * 4 + yb) * 8192;
        #pragma unroll
        for (int p = 0; p < 2; ++p)
            gload16(Wc + (size_t)(p * 512 + t) * 8, bB + (size_t)(p * 512 + t) * 8);
        if (t < 256) {
            const int row = t >> 2, q = t & 3;
            int node = n0 + row; if (node >= N_NODES) node = N_NODES - 1;
            gload16(hxin + (size_t)node * 512 + ((q ^ (row & 3)) * 8), bA + (size_t)t * 8);
        }
    }
    __syncthreads();

    #pragma unroll 1
    for (int c = 0; c < 8; ++c) {
        const int cur = c & 1;
        if (c < 7) {
            half_t* bB = lds + (cur ^ 1) * 10240; half_t* bA = bB + 8192;
            const half_t* Wc = Wy + (size_t)((layer * 8 + (c + 1)) * 4 + yb) * 8192;
            #pragma unroll
            for (int p = 0; p < 2; ++p)
                gload16(Wc + (size_t)(p * 512 + t) * 8, bB + (size_t)(p * 512 + t) * 8);
            if (t < 256) {
                const int row = t >> 2, q = t & 3;
                int node = n0 + row; if (node >= N_NODES) node = N_NODES - 1;
                gload16(hxin + (size_t)node * 512 + (c + 1) * 32 + ((q ^ (row & 3)) * 8),
                        bA + (size_t)t * 8);
            }
        }
        const half_t* bB = lds + cur * 10240;
        const half_t* bA = bB + 8192;
        f16x8 af[2];
        #pragma unroll
        for (int rt = 0; rt < 2; ++rt) {
            const int row = rh * 32 + rt * 16 + rl;
            af[rt] = *reinterpret_cast<const f16x8*>(&bA[(row * 4 + sw) * 8]);
        }
        #pragma unroll
        for (int nt = 0; nt < 4; ++nt) {
            const int cl = wc * 64 + nt * 16 + rl;
            f16x8 bf = *reinterpret_cast<const f16x8*>(&bB[(cl * 4 + sw) * 8]);
            #pragma unroll
            for (int rt = 0; rt < 2; ++rt)
                acc[rt][nt] = MFMA16(af[rt], bf, acc[rt][nt]);
        }
        __syncthreads();
    }

    // transpose epilogue (reuses lds): [64][264]
    const int rg = lane >> 4;
    #pragma unroll
    for (int rt = 0; rt < 2; ++rt)
        #pragma unroll
        for (int i = 0; i < 4; ++i) {
            const int row = rh * 32 + rt * 16 + rg * 4 + i;
            #pragma unroll
            for (int nt = 0; nt < 4; ++nt)
                lds[row * 264 + wc * 64 + nt * 16 + rl] = (half_t)acc[rt][nt][i];
        }
    __syncthreads();
    #pragma unroll
    for (int p = 0; p < 4; ++p) {
        const int g = p * 512 + t;
        const int row = g >> 5, q = g & 31;
        if (n0 + row < N_NODES)
            *reinterpret_cast<f16x8*>(&Y[(size_t)(n0 + row) * 1024 + yb * 256 + q * 8]) =
                *reinterpret_cast<const f16x8*>(&lds[row * 264 + q * 8]);
    }
}

// ---------------- k_gather: inc[v] = sum_t sum_e Y[src][t] + cnt_t * b_t ----------------
__global__ __launch_bounds__(256) void k_gather(
    const half_t* __restrict__ Y, const int* __restrict__ cnt,
    const int* __restrict__ elist, const float* __restrict__ b_msg,
    half_t* __restrict__ hx, int layer)
{
    const int wave = threadIdx.x >> 6, lane = threadIdx.x & 63;
    const int v = blockIdx.x * 4 + wave;
    if (v >= N_NODES) return;
    float s0 = 0.f, s1 = 0.f, s2 = 0.f, s3 = 0.f;
    const float4* bm = reinterpret_cast<const float4*>(b_msg + (size_t)layer * NTYPES * 256);
    #pragma unroll
    for (int t = 0; t < NTYPES; ++t) {
        const int slot = t * N_NODES + v;
        const int c = cnt[slot];
        const int cc = c < CAP ? c : CAP;
        const int* el = elist + (size_t)slot * CAP;
        for (int e = 0; e < cc; ++e) {
            const int src = el[e];
            f16x4 y = *reinterpret_cast<const f16x4*>(&Y[(size_t)src * 1024 + t * 256 + lane * 4]);
            s0 += (float)y[0]; s1 += (float)y[1]; s2 += (float)y[2]; s3 += (float)y[3];
        }
        float4 b = bm[t * 64 + lane];
        const float fc = (float)c;
        s0 += fc * b.x; s1 += fc * b.y; s2 += fc * b.z; s3 += fc * b.w;
    }
    f16x4 o; o[0] = (half_t)s0; o[1] = (half_t)s1; o[2] = (half_t)s2; o[3] = (half_t)s3;
    *reinterpret_cast<f16x4*>(&hx[(size_t)v * 512 + 256 + lane * 4]) = o;
}

// ---------------- k_gru2: fused GRU, B staged in LDS, ping-pong h state ----------------
// grid (782, 2): 64 rows x 128 h-cols (3 gates); 512 thr / 8 waves (rh2 x wc4); BK=32 x 16, dbuf
#define GRU_STAGE(cc, bb) do {                                                        \
    half_t* bB = lds + (bb) * 14336; half_t* bA = bB + 12288;                         \
    const half_t* Wc = Wg + (size_t)(((layer * 16 + (cc)) * 2) + yb) * 12288;         \
    _Pragma("unroll")                                                                 \
    for (int p = 0; p < 3; ++p)                                                       \
        gload16(Wc + (size_t)(p * 512 + t) * 8, bB + (size_t)(p * 512 + t) * 8);      \
    if (t < 256) {                                                                    \
        const int row = t >> 2, q = t & 3;                                            \
        int node = n0 + row; if (node >= N_NODES) node = N_NODES - 1;                 \
        gload16(hxin + (size_t)node * 512 + (cc) * 32 + ((q ^ (row & 3)) * 8),        \
                bA + (size_t)t * 8);                                                  \
    }                                                                                 \
} while (0)

__global__ __launch_bounds__(512) void k_gru2(
    const half_t* __restrict__ hxin, half_t* __restrict__ hxout,
    const half_t* __restrict__ Wg,
    const float* __restrict__ b_ih, const float* __restrict__ b_hh,
    int layer, int last)
{
    __shared__ __align__(16) half_t lds[2 * 14336];   // per buf: B 12288 + A 2048 halfs
    const int t = threadIdx.x, lane = t & 63;
    const int rh = (t >> 6) >> 2, wc = (t >> 6) & 3;
    const int n0 = blockIdx.x * 64, yb = blockIdx.y;
    const int kc = lane >> 4, rl = lane & 15;
    const int sw = kc ^ (rl & 3);

    f32x4 ar[2][2] = {}, az[2][2] = {}, ahn[2][2] = {}, ain[2][2] = {};

    GRU_STAGE(0, 0);
    __syncthreads();

    #pragma unroll 1
    for (int c = 0; c < 16; ++c) {
        const int cur = c & 1;
        if (c < 15) GRU_STAGE(c + 1, cur ^ 1);
        const half_t* bB = lds + cur * 14336;
        const half_t* bA = bB + 12288;
        f16x8 af[2];
        #pragma unroll
        for (int rt = 0; rt < 2; ++rt) {
            const int row = rh * 32 + rt * 16 + rl;
            af[rt] = *reinterpret_cast<const f16x8*>(&bA[(row * 4 + sw) * 8]);
        }
        #pragma unroll
        for (int nt = 0; nt < 2; ++nt) {
            const int cl = wc * 32 + nt * 16 + rl;
            f16x8 br = *reinterpret_cast<const f16x8*>(&bB[((      cl) * 4 + sw) * 8]);
            f16x8 bz = *reinterpret_cast<const f16x8*>(&bB[((128 + cl) * 4 + sw) * 8]);
            f16x8 b3 = *reinterpret_cast<const f16x8*>(&bB[((256 + cl) * 4 + sw) * 8]);
            if (c < 8) {
                #pragma unroll
                for (int rt = 0; rt < 2; ++rt) {
                    ar [rt][nt] = MFMA16(af[rt], br, ar [rt][nt]);
                    az [rt][nt] = MFMA16(af[rt], bz, az [rt][nt]);
                    ahn[rt][nt] = MFMA16(af[rt], b3, ahn[rt][nt]);
                }
            } else {
                #pragma unroll
                for (int rt = 0; rt < 2; ++rt) {
                    ar [rt][nt] = MFMA16(af[rt], br, ar [rt][nt]);
                    az [rt][nt] = MFMA16(af[rt], bz, az [rt][nt]);
                    ain[rt][nt] = MFMA16(af[rt], b3, ain[rt][nt]);
                }
            }
        }
        __syncthreads();
    }

    // GRU epilogue
    const int rg = lane >> 4;
    const float* bi = b_ih + layer * 768;
    const float* bh = b_hh + layer * 768;
    #pragma unroll
    for (int rt = 0; rt < 2; ++rt)
        #pragma unroll
        for (int i = 0; i < 4; ++i) {
            const int row = n0 + rh * 32 + rt * 16 + rg * 4 + i;
            const bool ok = row < N_NODES;
            #pragma unroll
            for (int nt = 0; nt < 2; ++nt) {
                const int cl = wc * 32 + nt * 16 + rl;
                const int col = yb * 128 + cl;
                float sr  = ar [rt][nt][i] + bi[col]       + bh[col];
                float sz  = az [rt][nt][i] + bi[256 + col] + bh[256 + col];
                float xin = ain[rt][nt][i] + bi[512 + col];
                float xhn = ahn[rt][nt][i] + bh[512 + col];
                float r = 1.f / (1.f + __expf(-sr));
                float z = 1.f / (1.f + __expf(-sz));
                float a = xin + r * xhn;
                float e2 = __expf(2.f * a);
                float n = (e2 - 1.f) / (e2 + 1.f);
                float hold = ok ? (float)hxin[(size_t)row * 512 + col] : 0.f;
                ar[rt][nt][i] = (1.f - z) * n + z * hold;
            }
        }

    if (!last) {
        // fp16 store via LDS transpose: [64][136]
        #pragma unroll
        for (int rt = 0; rt < 2; ++rt)
            #pragma unroll
            for (int i = 0; i < 4; ++i) {
                const int rr = rh * 32 + rt * 16 + rg * 4 + i;
                #pragma unroll
                for (int nt = 0; nt < 2; ++nt)
                    lds[rr * 136 + wc * 32 + nt * 16 + rl] = (half_t)ar[rt][nt][i];
            }
        __syncthreads();
        #pragma unroll
        for (int p = 0; p < 2; ++p) {
            const int g = p * 512 + t;
            const int row = g >> 4, q = g & 15;
            if (n0 + row < N_NODES)
                *reinterpret_cast<f16x8*>(&hxout[(size_t)(n0 + row) * 512 + yb * 128 + q * 8]) =
                    *reinterpret_cast<const f16x8*>(&lds[row * 136 + q * 8]);
        }
    } else {
        float* out = reinterpret_cast<float*>(hxout);
        #pragma unroll
        for (int rt = 0; rt < 2; ++rt)
            #pragma unroll
            for (int i = 0; i < 4; ++i) {
                const int row = n0 + rh * 32 + rt * 16 + rg * 4 + i;
                if (row >= N_NODES) continue;
                #pragma unroll
                for (int nt = 0; nt < 2; ++nt) {
                    const int cl = wc * 32 + nt * 16 + rl;
                    out[(size_t)row * 256 + yb * 128 + cl] = ar[rt][nt][i];
                }
            }
    }
}

// ---------------- launcher ----------------
extern "C" void kernel_launch(void* const* d_in, const int* in_sizes, int n_in,
                              void* d_out, int out_size, void* d_ws, size_t ws_size,
                              hipStream_t stream) {
    const float* x      = (const float*)d_in[0];
    const float* annot  = (const float*)d_in[1];
    const int*   edges  = (const int*)  d_in[2];
    const float* W_hid  = (const float*)d_in[3];
    const float* b_hid  = (const float*)d_in[4];
    const float* W_msg  = (const float*)d_in[5];
    const float* b_msg  = (const float*)d_in[6];
    const float* W_ih   = (const float*)d_in[7];
    const float* W_hh   = (const float*)d_in[8];
    const float* b_ih   = (const float*)d_in[9];
    const float* b_hh   = (const float*)d_in[10];

    // h state ping-pongs: hA lives in d_out (final fp32 lands there), hB in ws
    half_t* hA = (half_t*)d_out;

    char* ws = (char*)d_ws;
    size_t off = 0;
    auto alloc = [&](size_t bytes) -> char* {
        char* p = ws + off;
        off = (off + bytes + 255) & ~(size_t)255;
        return p;
    };
    half_t* hB     = (half_t*)alloc((size_t)N_NODES * 512 * 2);           // 51.2 MB
    half_t* Y      = (half_t*)alloc((size_t)N_NODES * 1024 * 2);          // 102.4 MB
    int*    elist  = (int*)   alloc((size_t)NTYPES * N_NODES * CAP * 4);  // 12.8 MB
    int*    cnt    = (int*)   alloc((size_t)NTYPES * N_NODES * 4);        // 0.8 MB
    half_t* Whid16 = (half_t*)alloc((size_t)256 * 288 * 2);
    half_t* Wg     = (half_t*)alloc((size_t)786432 * 2);
    half_t* Wy     = (half_t*)alloc((size_t)524288 * 2);
    (void)ws_size;

    hipMemsetAsync(cnt, 0, (size_t)NTYPES * N_NODES * 4, stream);
    k_csr<<<dim3((NTYPES * EPT + 255) / 256), 256, 0, stream>>>(edges, cnt, elist);
    k_cvt<<<dim3((73728 + 255) / 256), 256, 0, stream>>>(W_hid, Whid16, 73728);
    k_cvt_wg<<<dim3(786432 / 256), 256, 0, stream>>>(W_ih, W_hh, Wg);
    k_cvt_wy<<<dim3(524288 / 256), 256, 0, stream>>>(W_msg, Wy);

    const int NB = (N_NODES + 63) / 64;   // 782
    k_init<<<dim3(NB), 256, 0, stream>>>(x, annot, Whid16, b_hid, hA);

    for (int step = 0; step < 6; ++step) {
        const int layer = step / 3;
        half_t* hin  = (step & 1) ? hB : hA;
        half_t* hout = (step & 1) ? hA : hB;
        const int last = (step == 5) ? 1 : 0;
        k_y2<<<dim3(NB, 4), 512, 0, stream>>>(hin, Wy, Y, layer);
        k_gather<<<dim3((N_NODES + 3) / 4), 256, 0, stream>>>(Y, cnt, elist, b_msg, hin, layer);
        k_gru2<<<dim3(NB, 2), 512, 0, stream>>>(hin, last ? hA : hout, Wg, b_ih, b_hh, layer, last);
    }
}